// Round 9
// baseline (888.815 us; speedup 1.0000x reference)
//
#include <hip/hip_runtime.h>
#include <math.h>

// ---- problem constants ----
constexpr int kHF = 361, kWF = 720;       // full grid
constexpr int kHP = 90,  kWP = 180;       // processor grid
constexpr int kCIN = 26, kCE = 48, kCOUT = 24;
constexpr int kK = 9, kNB = 6;
constexpr int kL = 90, kM = 90;
constexpr int kNL = 4, kHD = 96;
constexpr int kNP  = kHP * kWP;           // 16200
constexpr int kNPF = kHF * kWF;           // 259920

#ifndef M_PI
#define M_PI 3.14159265358979323846
#endif

// ---------------- prep 1: DFT tables (float2 packed) + decoder weight transpose ----------------
__global__ __launch_bounds__(256) void k_prep1(float2* __restrict__ fcs, float2* __restrict__ icn,
                                               const float* __restrict__ dw, float* __restrict__ dwT) {
    int t = blockIdx.x * 256 + threadIdx.x;
    if (t < kM * kWP) {
        int m = t / kWP, w = t % kWP;
        double th = (2.0 * M_PI / (double)kWP) * (double)(m * w);
        double c = cos(th), s = sin(th);
        fcs[w * kM + m] = make_float2((float)(c / (double)kWP), (float)(-s / (double)kWP));
        float sc = (m == 0) ? 1.0f : 2.0f;
        icn[m * kWP + w] = make_float2(sc * (float)c, sc * (float)s);
    }
    if (t < kCOUT * kCE * kK) {
        int k = t % kK;
        int i = (t / kK) % kCE;
        int o = t / (kK * kCE);
        dwT[((size_t)i * kCOUT + o) * kK + k] = dw[t];
    }
}

// ---------------- prep 2: transpose both Legendre matrices ----------------
__global__ __launch_bounds__(256) void k_prep2(const float* __restrict__ Pw, const float* __restrict__ Pi,
                                               float* __restrict__ PwT, float* __restrict__ PiT) {
    int t = blockIdx.x * 256 + threadIdx.x;
    int N = kL * kM * kHP;
    if (t >= 2 * N) return;
    int mode = t >= N ? 1 : 0;
    int u = mode ? t - N : t;
    int l = u / (kM * kHP);
    int r = u % (kM * kHP);
    int m = r / kHP;
    int tt = r % kHP;
    if (mode == 0) PwT[(l * kHP + tt) * kM + m] = Pw[u];
    else           PiT[(tt * kL + l) * kM + m] = Pi[u];
}

// ---------------- disco conv (encoder / processor), software-pipelined ----------------
template <int TCIN, int TCOUT, int OG>
__global__ __launch_bounds__(256) void k_disco(const float* __restrict__ src, int srcStride,
                                               const int* __restrict__ idx, const float* __restrict__ vals,
                                               const float* __restrict__ w, float* __restrict__ out, int np) {
    int gt = blockIdx.x * 256 + threadIdx.x;
    if (gt >= np * OG) return;
    int p = gt % np;
    int og = gt / np;
    constexpr int OC = TCOUT / OG;

    int qi[kNB];
#pragma unroll
    for (int n = 0; n < kNB; n++) qi[n] = idx[p * kNB + n];

    float vv[kK][kNB];
#pragma unroll
    for (int k = 0; k < kK; k++) {
        const float* vp = vals + ((size_t)k * np + p) * kNB;
#pragma unroll
        for (int n = 0; n < kNB; n += 2) {
            float2 v2 = *(const float2*)(vp + n);
            vv[k][n] = v2.x; vv[k][n + 1] = v2.y;
        }
    }

    float acc[OC];
#pragma unroll
    for (int o = 0; o < OC; o++) acc[o] = 0.0f;

    const float* wbase = w + (size_t)og * OC * TCIN * kK;

    // software pipeline: prefetch next channel's gathers
    float xg[kNB];
#pragma unroll
    for (int n = 0; n < kNB; n++) xg[n] = src[qi[n]];

#pragma unroll 2
    for (int i = 0; i < TCIN; i++) {
        float xgn[kNB];
        if (i + 1 < TCIN) {
            const float* sn = src + (size_t)(i + 1) * srcStride;
#pragma unroll
            for (int n = 0; n < kNB; n++) xgn[n] = sn[qi[n]];
        }
        float z[kK];
#pragma unroll
        for (int k = 0; k < kK; k++) {
            float zz = 0.0f;
#pragma unroll
            for (int n = 0; n < kNB; n++) zz = fmaf(vv[k][n], xg[n], zz);
            z[k] = zz;
        }
#pragma unroll
        for (int o = 0; o < OC; o++) {
            const float* wp = wbase + ((size_t)o * TCIN + i) * kK;
            float s = acc[o];
#pragma unroll
            for (int k = 0; k < kK; k++) s = fmaf(wp[k], z[k], s);
            acc[o] = s;
        }
#pragma unroll
        for (int n = 0; n < kNB; n++) xg[n] = xgn[n];
    }
#pragma unroll
    for (int o = 0; o < OC; o++) out[(size_t)(og * OC + o) * np + p] = acc[o];
}

// ---------------- spectral pipeline (float2 complex, unrolled) ----------------
// S1: rfft rows; g row staged in LDS
__global__ __launch_bounds__(256) void k_rfft2(const float* __restrict__ g, const float2* __restrict__ fcs,
                                               float2* __restrict__ xc) {
    __shared__ float gs[4 * kWP];
    int t0 = blockIdx.x * 256;
    int t = t0 + threadIdx.x;
    int r0 = t0 / kM;
    int r1 = (t0 + 255) / kM;
    int nrows = r1 - r0 + 1;  // <= 4
    for (int j = threadIdx.x; j < nrows * kWP; j += 256) {
        int rr = j / kWP, w = j % kWP;
        int row = r0 + rr;
        if (row < kCE * kHP) gs[j] = g[(size_t)row * kWP + w];
    }
    __syncthreads();
    if (t >= kCE * kHP * kM) return;
    int m = t % kM;
    int row = t / kM;
    const float* gr = &gs[(row - r0) * kWP];
    float ar = 0.0f, ai = 0.0f;
#pragma unroll 6
    for (int w = 0; w < kWP; w++) {
        float gv = gr[w];
        float2 f = fcs[w * kM + m];
        ar = fmaf(gv, f.x, ar);
        ai = fmaf(gv, f.y, ai);
    }
    xc[t] = make_float2(ar, ai);
}

// S2: c[c,l,m] = sum_t PwT[(l*90+t)*90+m] * xc[c,t,m]
__global__ __launch_bounds__(256) void k_sht2(const float* __restrict__ PwT, const float2* __restrict__ xc,
                                              float2* __restrict__ cc) {
    int t = blockIdx.x * 256 + threadIdx.x;
    if (t >= kCE * kL * kM) return;
    int m = t % kM;
    int l = (t / kM) % kL;
    int c = t / (kM * kL);
    float ar = 0.0f, ai = 0.0f;
#pragma unroll 6
    for (int tt = 0; tt < kHP; tt++) {
        float pv = PwT[((size_t)l * kHP + tt) * kM + m];
        float2 xv = xc[((size_t)c * kHP + tt) * kM + m];
        ar = fmaf(pv, xv.x, ar);
        ai = fmaf(pv, xv.y, ai);
    }
    cc[t] = make_float2(ar, ai);
}

// S3: c2[o,l,m] = sum_i gw[o,i,l] * cc[i,l,m]
__global__ __launch_bounds__(256) void k_gmix2(const float* __restrict__ gwl, const float2* __restrict__ cc,
                                               float2* __restrict__ c2c) {
    int t = blockIdx.x * 256 + threadIdx.x;
    if (t >= kCE * kL * kM) return;
    int m = t % kM;
    int l = (t / kM) % kL;
    int o = t / (kM * kL);
    float ar = 0.0f, ai = 0.0f;
#pragma unroll 8
    for (int i = 0; i < kCE; i++) {
        float gv = gwl[((size_t)o * kCE + i) * kL + l];
        float2 cv = cc[((size_t)i * kL + l) * kM + m];
        ar = fmaf(gv, cv.x, ar);
        ai = fmaf(gv, cv.y, ai);
    }
    c2c[t] = make_float2(ar, ai);
}

// S4: xc[c,t,m] = sum_l PiT[(t*90+l)*90+m] * c2c[c,l,m]  (overwrites xc)
__global__ __launch_bounds__(256) void k_isht2(const float* __restrict__ PiT, const float2* __restrict__ c2c,
                                               float2* __restrict__ xc) {
    int t = blockIdx.x * 256 + threadIdx.x;
    if (t >= kCE * kHP * kM) return;
    int m = t % kM;
    int tt = (t / kM) % kHP;
    int c = t / (kM * kHP);
    float ar = 0.0f, ai = 0.0f;
#pragma unroll 6
    for (int l = 0; l < kL; l++) {
        float pv = PiT[((size_t)tt * kL + l) * kM + m];
        float2 cv = c2c[((size_t)c * kL + l) * kM + m];
        ar = fmaf(pv, cv.x, ar);
        ai = fmaf(pv, cv.y, ai);
    }
    xc[t] = make_float2(ar, ai);
}

// S5: dx[row,w] = sum_m (xc.x*icn.x - xc.y*icn.y)
__global__ __launch_bounds__(256) void k_irfft2(const float2* __restrict__ xc, const float2* __restrict__ icn,
                                                float* __restrict__ dx) {
    int t = blockIdx.x * 256 + threadIdx.x;
    if (t >= kCE * kHP * kWP) return;
    int w = t % kWP;
    int row = t / kWP;
    const float2* xr = xc + (size_t)row * kM;
    float a = 0.0f;
#pragma unroll 6
    for (int m = 0; m < kM; m++) {
        float2 x = xr[m];            // wave-broadcast (row uniform within wave)
        float2 f = icn[m * kWP + w]; // coalesced across w
        a = fmaf(x.x, f.x, a);
        a = fmaf(-x.y, f.y, a);
    }
    dx[t] = a;
}

// ---------------- MLP (split, unrolled) ----------------
__device__ __forceinline__ float gelu_tanh(float x) {
    float x3 = x * x * x;
    float t = tanhf(0.7978845608028654f * (x + 0.044715f * x3));
    return 0.5f * x * (1.0f + t);
}

__global__ __launch_bounds__(256) void k_mlp1(const float* __restrict__ m1w, const float* __restrict__ dx,
                                              float* __restrict__ dx1) {
    int t = blockIdx.x * 256 + threadIdx.x;
    if (t >= kHD * kNP) return;
    int p = t % kNP;
    int hh = t / kNP;
    float a = 0.0f;
#pragma unroll 8
    for (int i = 0; i < kCE; i++) a = fmaf(m1w[hh * kCE + i], dx[(size_t)i * kNP + p], a);
    dx1[t] = gelu_tanh(a);
}

__global__ __launch_bounds__(256) void k_mlp2(const float* __restrict__ m2w, const float* __restrict__ lsw,
                                              const float* __restrict__ dx1, float* __restrict__ h) {
    int t = blockIdx.x * 256 + threadIdx.x;
    if (t >= kCE * kNP) return;
    int p = t % kNP;
    int o = t / kNP;
    float a = 0.0f;
#pragma unroll 8
    for (int j = 0; j < kHD; j++) a = fmaf(m2w[o * kHD + j], dx1[(size_t)j * kNP + p], a);
    h[t] = h[t] + lsw[o] * a;
}

// ---------------- decoder: per-point 3x3 stencil, direct from global, pipelined ----------------
__global__ __launch_bounds__(256) void k_dconv_d(const float* __restrict__ h,
                                                 const float* __restrict__ dvals,
                                                 const float* __restrict__ dwT,
                                                 const int* __restrict__ li0, const int* __restrict__ li1,
                                                 const float* __restrict__ lwt, const int* __restrict__ oi0,
                                                 const int* __restrict__ oi1, const float* __restrict__ owt,
                                                 float* __restrict__ out) {
    int p = blockIdx.x * 256 + threadIdx.x;
    if (p >= kNPF) return;
    int lat = p / kWF;
    int p_lon = p - lat * kWF;

    // latitude: output rows lat-1..lat+1 (clipped) -> patch rows F..F+2
    int i0r[3], i1r[3];
    float awr[3];
#pragma unroll
    for (int r = 0; r < 3; r++) {
        int Lr = lat - 1 + r;
        Lr = Lr < 0 ? 0 : (Lr > kHF - 1 ? kHF - 1 : Lr);
        i0r[r] = li0[Lr]; i1r[r] = li1[Lr]; awr[r] = lwt[Lr];
    }
    int F = min(i0r[0], min(i0r[1], i0r[2]));

    float wrow[3][3];
#pragma unroll
    for (int r = 0; r < 3; r++) {
        int r0 = i0r[r] - F, r1 = i1r[r] - F;
#pragma unroll
        for (int pr = 0; pr < 3; pr++) {
            float wv = 0.0f;
            if (pr == r0) wv += 1.0f - awr[r];
            if (pr == r1) wv += awr[r];
            wrow[r][pr] = wv;
        }
    }

    // longitude: output cols lon-1..lon+1 (periodic) -> patch cols G..G+2
    int o0d[3], o1d[3];
    float owd[3];
#pragma unroll
    for (int d = 0; d < 3; d++) {
        int lm = (p_lon + d - 1 + kWF) % kWF;
        o0d[d] = oi0[lm]; o1d[d] = oi1[lm]; owd[d] = owt[lm];
    }
    int G = o0d[0];
    float wcol[3][3];
#pragma unroll
    for (int d = 0; d < 3; d++) {
        int c0 = (o0d[d] - G + kWP) % kWP;
        int c1 = (o1d[d] - G + kWP) % kWP;
#pragma unroll
        for (int pc = 0; pc < 3; pc++) {
            float wv = 0.0f;
            if (pc == c0) wv += 1.0f - owd[d];
            if (pc == c1) wv += owd[d];
            wcol[d][pc] = wv;
        }
    }

    // psi vals
    float vv[kK][kNB];
#pragma unroll
    for (int k = 0; k < kK; k++) {
        const float* vp = dvals + ((size_t)k * kNPF + p) * kNB;
#pragma unroll
        for (int n = 0; n < kNB; n += 2) {
            float2 v2 = *(const float2*)(vp + n);
            vv[k][n] = v2.x; vv[k][n + 1] = v2.y;
        }
    }

    // collapse psi x bilinear into ck[k][3][3]
    const int RR[kNB] = {1, 1, 1, 2, 0, 2};
    const int CC[kNB] = {1, 2, 0, 1, 1, 2};
    float ck[kK][3][3];
#pragma unroll
    for (int k = 0; k < kK; k++)
#pragma unroll
        for (int pr = 0; pr < 3; pr++)
#pragma unroll
            for (int pc = 0; pc < 3; pc++) {
                float s = 0.0f;
#pragma unroll
                for (int n = 0; n < kNB; n++)
                    s = fmaf(vv[k][n], wrow[RR[n]][pr] * wcol[CC[n]][pc], s);
                ck[k][pr][pc] = s;
            }

    // 9 patch offsets (channel 0); +kNP per channel
    int ofs[3][3];
#pragma unroll
    for (int pr = 0; pr < 3; pr++) {
        int row = F + pr; row = row > kHP - 1 ? kHP - 1 : row;
#pragma unroll
        for (int pc = 0; pc < 3; pc++) {
            int col = (G + pc) % kWP;
            ofs[pr][pc] = row * kWP + col;
        }
    }

    float acc[kCOUT];
#pragma unroll
    for (int o = 0; o < kCOUT; o++) acc[o] = 0.0f;

    // software pipeline: prefetch channel i+1's 9 loads before computing channel i
    float hva[3][3];
#pragma unroll
    for (int pr = 0; pr < 3; pr++)
#pragma unroll
        for (int pc = 0; pc < 3; pc++)
            hva[pr][pc] = h[ofs[pr][pc]];

    const float* wp = dwT;
    const float* hi = h;
#pragma unroll 2
    for (int i = 0; i < kCE; i++) {
        float hvb[3][3];
        if (i + 1 < kCE) {
            const float* hn = hi + kNP;
#pragma unroll
            for (int pr = 0; pr < 3; pr++)
#pragma unroll
                for (int pc = 0; pc < 3; pc++)
                    hvb[pr][pc] = hn[ofs[pr][pc]];
        }
        float z[kK];
#pragma unroll
        for (int k = 0; k < kK; k++) {
            float s = 0.0f;
#pragma unroll
            for (int pr = 0; pr < 3; pr++)
#pragma unroll
                for (int pc = 0; pc < 3; pc++)
                    s = fmaf(ck[k][pr][pc], hva[pr][pc], s);
            z[k] = s;
        }
#pragma unroll
        for (int o = 0; o < kCOUT; o++) {
            float s = acc[o];
#pragma unroll
            for (int k = 0; k < kK; k++) s = fmaf(wp[o * kK + k], z[k], s);
            acc[o] = s;
        }
#pragma unroll
        for (int pr = 0; pr < 3; pr++)
#pragma unroll
            for (int pc = 0; pc < 3; pc++)
                hva[pr][pc] = hvb[pr][pc];
        wp += kCOUT * kK;
        hi += kNP;
    }

#pragma unroll
    for (int o = 0; o < kCOUT; o++) out[(size_t)o * kNPF + p] = acc[o];
}

// ---------------- host launcher ----------------
extern "C" void kernel_launch(void* const* d_in, const int* in_sizes, int n_in,
                              void* d_out, int out_size, void* d_ws, size_t ws_size,
                              hipStream_t stream) {
    const float* x         = (const float*)d_in[0];
    const int*   enc_idx   = (const int*)d_in[1];
    const float* enc_vals  = (const float*)d_in[2];
    const float* enc_w     = (const float*)d_in[3];
    const int*   proc_idx  = (const int*)d_in[4];
    const float* proc_vals = (const float*)d_in[5];
    const float* lw        = (const float*)d_in[6];
    const float* gw        = (const float*)d_in[7];
    const float* Pw        = (const float*)d_in[8];
    const float* Pi        = (const float*)d_in[9];
    const float* m1        = (const float*)d_in[10];
    const float* m2        = (const float*)d_in[11];
    const float* ls        = (const float*)d_in[12];
    const int*   li0       = (const int*)d_in[13];
    const int*   li1       = (const int*)d_in[14];
    const float* lwt       = (const float*)d_in[15];
    const int*   oi0       = (const int*)d_in[16];
    const int*   oi1       = (const int*)d_in[17];
    const float* owt       = (const float*)d_in[18];
    const int*   dec_idx   = (const int*)d_in[19];
    const float* dec_vals  = (const float*)d_in[20];
    const float* dec_w     = (const float*)d_in[21];
    float* out = (float*)d_out;
    (void)dec_idx;

    float* ws = (float*)d_ws;
    size_t off = 0;
    auto alloc = [&](size_t n) { float* p = ws + off; off += n; return p; };
    float*  h    = alloc((size_t)kCE * kNP);
    float2* xc   = (float2*)alloc((size_t)2 * kCE * kHP * kM);
    float2* cc   = (float2*)alloc((size_t)2 * kCE * kL * kM);
    float2* c2c  = (float2*)alloc((size_t)2 * kCE * kL * kM);
    float*  dx   = alloc((size_t)kCE * kNP);
    float*  dx1  = alloc((size_t)kHD * kNP);
    float2* fcs  = (float2*)alloc((size_t)2 * kM * kWP);
    float2* icn  = (float2*)alloc((size_t)2 * kM * kWP);
    float*  PwT  = alloc((size_t)kL * kM * kHP);
    float*  PiT  = alloc((size_t)kL * kM * kHP);
    float*  dwT  = alloc((size_t)kCOUT * kCE * kK);
    (void)ws_size; (void)in_sizes; (void)n_in; (void)out_size;

    dim3 B(256);
    auto nb = [](long long n) { return dim3((unsigned)((n + 255) / 256)); };

    k_prep1<<<nb(kM * kWP), B, 0, stream>>>(fcs, icn, dec_w, dwT);
    k_prep2<<<nb(2LL * kL * kM * kHP), B, 0, stream>>>(Pw, Pi, PwT, PiT);

    // encoder
    k_disco<kCIN, kCE, 8><<<nb((long long)kNP * 8), B, 0, stream>>>(
        x, kNPF, enc_idx, enc_vals, enc_w, h, kNP);

    for (int i = 0; i < kNL; i++) {
        if (i % 2 == 0) {
            const float* gwl = gw + (size_t)(i / 2) * kCE * kCE * kL;
            k_rfft2<<<nb((long long)kCE * kHP * kM), B, 0, stream>>>(h, fcs, xc);
            k_sht2<<<nb((long long)kCE * kL * kM), B, 0, stream>>>(PwT, xc, cc);
            k_gmix2<<<nb((long long)kCE * kL * kM), B, 0, stream>>>(gwl, cc, c2c);
            k_isht2<<<nb((long long)kCE * kHP * kM), B, 0, stream>>>(PiT, c2c, xc);
            k_irfft2<<<nb((long long)kCE * kHP * kWP), B, 0, stream>>>(xc, icn, dx);
        } else {
            const float* lwl = lw + (size_t)(i / 2) * kCE * kCE * kK;
            k_disco<kCE, kCE, 8><<<nb((long long)kNP * 8), B, 0, stream>>>(
                h, kNP, proc_idx, proc_vals, lwl, dx, kNP);
        }
        k_mlp1<<<nb((long long)kHD * kNP), B, 0, stream>>>(m1 + (size_t)i * kHD * kCE, dx, dx1);
        k_mlp2<<<nb((long long)kCE * kNP), B, 0, stream>>>(m2 + (size_t)i * kCE * kHD, ls + (size_t)i * kCE, dx1, h);
    }

    // decoder: per-point 3x3 stencil, direct from global, software-pipelined
    k_dconv_d<<<nb((long long)kNPF), B, 0, stream>>>(h, dec_vals, dwT,
                                                     li0, li1, lwt, oi0, oi1, owt, out);
}

// Round 10
// 806.181 us; speedup vs baseline: 1.1025x; 1.1025x over previous
//
#include <hip/hip_runtime.h>
#include <math.h>

// ---- problem constants ----
constexpr int kHF = 361, kWF = 720;       // full grid
constexpr int kHP = 90,  kWP = 180;       // processor grid
constexpr int kCIN = 26, kCE = 48, kCOUT = 24;
constexpr int kK = 9, kNB = 6;
constexpr int kL = 90, kM = 90;
constexpr int kNL = 4, kHD = 96;
constexpr int kNP  = kHP * kWP;           // 16200
constexpr int kNPF = kHF * kWF;           // 259920

#ifndef M_PI
#define M_PI 3.14159265358979323846
#endif

// ---------------- prep 1: DFT tables (float2 packed) + decoder weight transpose ----------------
__global__ __launch_bounds__(256) void k_prep1(float2* __restrict__ fcs, float2* __restrict__ icn,
                                               const float* __restrict__ dw, float* __restrict__ dwT) {
    int t = blockIdx.x * 256 + threadIdx.x;
    if (t < kM * kWP) {
        int m = t / kWP, w = t % kWP;
        double th = (2.0 * M_PI / (double)kWP) * (double)(m * w);
        double c = cos(th), s = sin(th);
        fcs[w * kM + m] = make_float2((float)(c / (double)kWP), (float)(-s / (double)kWP));
        float sc = (m == 0) ? 1.0f : 2.0f;
        icn[m * kWP + w] = make_float2(sc * (float)c, sc * (float)s);
    }
    if (t < kCOUT * kCE * kK) {
        int k = t % kK;
        int i = (t / kK) % kCE;
        int o = t / (kK * kCE);
        dwT[((size_t)i * kCOUT + o) * kK + k] = dw[t];
    }
}

// ---------------- prep 2: transpose both Legendre matrices ----------------
__global__ __launch_bounds__(256) void k_prep2(const float* __restrict__ Pw, const float* __restrict__ Pi,
                                               float* __restrict__ PwT, float* __restrict__ PiT) {
    int t = blockIdx.x * 256 + threadIdx.x;
    int N = kL * kM * kHP;
    if (t >= 2 * N) return;
    int mode = t >= N ? 1 : 0;
    int u = mode ? t - N : t;
    int l = u / (kM * kHP);
    int r = u % (kM * kHP);
    int m = r / kHP;
    int tt = r % kHP;
    if (mode == 0) PwT[(l * kHP + tt) * kM + m] = Pw[u];
    else           PiT[(tt * kL + l) * kM + m] = Pi[u];
}

// ---------------- disco conv (encoder / processor): round-8 simple form ----------------
// (manual software pipelining regressed -35% in round 9 — compiler schedules better)
template <int TCIN, int TCOUT, int OG>
__global__ __launch_bounds__(256) void k_disco(const float* __restrict__ src, int srcStride,
                                               const int* __restrict__ idx, const float* __restrict__ vals,
                                               const float* __restrict__ w, float* __restrict__ out, int np) {
    int gt = blockIdx.x * 256 + threadIdx.x;
    if (gt >= np * OG) return;
    int p = gt % np;
    int og = gt / np;
    constexpr int OC = TCOUT / OG;

    int qi[kNB];
#pragma unroll
    for (int n = 0; n < kNB; n++) qi[n] = idx[p * kNB + n];

    float vv[kK][kNB];
#pragma unroll
    for (int k = 0; k < kK; k++) {
        const float* vp = vals + ((size_t)k * np + p) * kNB;
#pragma unroll
        for (int n = 0; n < kNB; n += 2) {
            float2 v2 = *(const float2*)(vp + n);
            vv[k][n] = v2.x; vv[k][n + 1] = v2.y;
        }
    }

    float acc[OC];
#pragma unroll
    for (int o = 0; o < OC; o++) acc[o] = 0.0f;

    const float* wbase = w + (size_t)og * OC * TCIN * kK;

    for (int i = 0; i < TCIN; i++) {
        float xg[kNB];
#pragma unroll
        for (int n = 0; n < kNB; n++) xg[n] = src[i * srcStride + qi[n]];
        float z[kK];
#pragma unroll
        for (int k = 0; k < kK; k++) {
            float zz = 0.0f;
#pragma unroll
            for (int n = 0; n < kNB; n++) zz = fmaf(vv[k][n], xg[n], zz);
            z[k] = zz;
        }
#pragma unroll
        for (int o = 0; o < OC; o++) {
            const float* wp = wbase + ((size_t)o * TCIN + i) * kK;
            float s = acc[o];
#pragma unroll
            for (int k = 0; k < kK; k++) s = fmaf(wp[k], z[k], s);
            acc[o] = s;
        }
    }
#pragma unroll
    for (int o = 0; o < OC; o++) out[(size_t)(og * OC + o) * np + p] = acc[o];
}

// ---------------- spectral stage 1: rfft rows (LDS-staged g) ----------------
__global__ __launch_bounds__(256) void k_rfft2(const float* __restrict__ g, const float2* __restrict__ fcs,
                                               float2* __restrict__ xc) {
    __shared__ float gs[4 * kWP];
    int t0 = blockIdx.x * 256;
    int t = t0 + threadIdx.x;
    int r0 = t0 / kM;
    int r1 = (t0 + 255) / kM;
    int nrows = r1 - r0 + 1;  // <= 4
    for (int j = threadIdx.x; j < nrows * kWP; j += 256) {
        int rr = j / kWP, w = j % kWP;
        int row = r0 + rr;
        if (row < kCE * kHP) gs[j] = g[(size_t)row * kWP + w];
    }
    __syncthreads();
    if (t >= kCE * kHP * kM) return;
    int m = t % kM;
    int row = t / kM;
    const float* gr = &gs[(row - r0) * kWP];
    float ar = 0.0f, ai = 0.0f;
#pragma unroll 6
    for (int w = 0; w < kWP; w++) {
        float gv = gr[w];
        float2 f = fcs[w * kM + m];
        ar = fmaf(gv, f.x, ar);
        ai = fmaf(gv, f.y, ai);
    }
    xc[t] = make_float2(ar, ai);
}

// ---------------- spectral stage 2+3 fused: SHT + channel mix ----------------
// Block = one (l, m-tile of 18). Stage1 computes c[i,l,m] into LDS; stage2 mixes
// channels from LDS and writes c2c. Kills the cc global round trip and the
// 48x-redundant gmix re-reads.
constexpr int kMT = 18;  // 90 = 5 * 18
__global__ __launch_bounds__(256) void k_sht_gmix(const float* __restrict__ PwT,
                                                  const float2* __restrict__ xc,
                                                  const float* __restrict__ gwl,
                                                  float2* __restrict__ c2c) {
    __shared__ float2 cs[kCE][kMT];   // 6.9 KB
    int l = blockIdx.x / 5;
    int m0 = (blockIdx.x % 5) * kMT;
    int tid = threadIdx.x;

    for (int j = tid; j < kCE * kMT; j += 256) {
        int i = j / kMT, mm = j % kMT;
        int m = m0 + mm;
        float ar = 0.0f, ai = 0.0f;
        const float*  pw = PwT + (size_t)l * kHP * kM + m;
        const float2* xv = xc + (size_t)i * kHP * kM + m;
#pragma unroll 6
        for (int tt = 0; tt < kHP; tt++) {
            float pv = pw[tt * kM];
            float2 x = xv[tt * kM];
            ar = fmaf(pv, x.x, ar);
            ai = fmaf(pv, x.y, ai);
        }
        cs[i][mm] = make_float2(ar, ai);
    }
    __syncthreads();
    for (int j = tid; j < kCE * kMT; j += 256) {
        int o = j / kMT, mm = j % kMT;
        float ar = 0.0f, ai = 0.0f;
        const float* gv = gwl + (size_t)o * kCE * kL + l;
#pragma unroll 8
        for (int i = 0; i < kCE; i++) {
            float g = gv[(size_t)i * kL];
            float2 cv = cs[i][mm];
            ar = fmaf(g, cv.x, ar);
            ai = fmaf(g, cv.y, ai);
        }
        c2c[((size_t)o * kL + l) * kM + m0 + mm] = make_float2(ar, ai);
    }
}

// ---------------- spectral stage 4+5 fused: iSHT + irfft ----------------
// Block = one (c,t) row. Phase 1 (90 threads): xm[m] = sum_l PiT*c2c into LDS.
// Phase 2 (180 threads): dx[w] = sum_m Re(xm * conj-table). Kills the xc round
// trip; xm reads are same-address LDS broadcast.
__global__ __launch_bounds__(192) void k_isht_irfft(const float* __restrict__ PiT,
                                                    const float2* __restrict__ c2c,
                                                    const float2* __restrict__ icn,
                                                    float* __restrict__ dx) {
    __shared__ float2 xm[kM];  // 720 B
    int c = blockIdx.x / kHP;
    int t = blockIdx.x % kHP;
    int tid = threadIdx.x;

    if (tid < kM) {
        int m = tid;
        float ar = 0.0f, ai = 0.0f;
        const float*  pv = PiT + (size_t)t * kL * kM + m;
        const float2* cv = c2c + (size_t)c * kL * kM + m;
#pragma unroll 6
        for (int l = 0; l < kL; l++) {
            float p = pv[(size_t)l * kM];
            float2 cc2 = cv[(size_t)l * kM];
            ar = fmaf(p, cc2.x, ar);
            ai = fmaf(p, cc2.y, ai);
        }
        xm[m] = make_float2(ar, ai);
    }
    __syncthreads();
    if (tid < kWP) {
        int w = tid;
        float a = 0.0f;
#pragma unroll 6
        for (int m = 0; m < kM; m++) {
            float2 x = xm[m];            // broadcast
            float2 f = icn[m * kWP + w]; // coalesced
            a = fmaf(x.x, f.x, a);
            a = fmaf(-x.y, f.y, a);
        }
        dx[((size_t)c * kHP + t) * kWP + w] = a;
    }
}

// ---------------- fused MLP: h += ls * m2 @ gelu(m1 @ dx), LDS-tiled ----------------
__device__ __forceinline__ float gelu_tanh(float x) {
    float x3 = x * x * x;
    float t = tanhf(0.7978845608028654f * (x + 0.044715f * x3));
    return 0.5f * x * (1.0f + t);
}

constexpr int kTP = 32;  // points per block
__global__ __launch_bounds__(256) void k_mlp_f(const float* __restrict__ m1w, const float* __restrict__ m2w,
                                               const float* __restrict__ lsw, const float* __restrict__ dx,
                                               float* __restrict__ h) {
    __shared__ float xs[kCE][kTP];   // 6 KB
    __shared__ float g1[kHD][kTP];   // 12 KB
    int p0 = blockIdx.x * kTP;
    int tid = threadIdx.x;

    for (int j = tid; j < kCE * kTP; j += 256) {
        int i = j / kTP, pp = j % kTP;
        int p = p0 + pp;
        xs[i][pp] = (p < kNP) ? dx[(size_t)i * kNP + p] : 0.0f;
    }
    __syncthreads();
    for (int j = tid; j < kHD * kTP; j += 256) {
        int hh = j / kTP, pp = j % kTP;
        const float* w1 = m1w + (size_t)hh * kCE;
        float a = 0.0f;
#pragma unroll 8
        for (int i = 0; i < kCE; i++) a = fmaf(w1[i], xs[i][pp], a);
        g1[hh][pp] = gelu_tanh(a);
    }
    __syncthreads();
    for (int j = tid; j < kCE * kTP; j += 256) {
        int o = j / kTP, pp = j % kTP;
        int p = p0 + pp;
        if (p < kNP) {
            const float* w2 = m2w + (size_t)o * kHD;
            float a = 0.0f;
#pragma unroll 8
            for (int jj = 0; jj < kHD; jj++) a = fmaf(w2[jj], g1[jj][pp], a);
            size_t q = (size_t)o * kNP + p;
            h[q] = h[q] + lsw[o] * a;
        }
    }
}

// ---------------- decoder: per-point 3x3 stencil, direct from global (round-8 form) ----------------
__global__ __launch_bounds__(256) void k_dconv_d(const float* __restrict__ h,
                                                 const float* __restrict__ dvals,
                                                 const float* __restrict__ dwT,
                                                 const int* __restrict__ li0, const int* __restrict__ li1,
                                                 const float* __restrict__ lwt, const int* __restrict__ oi0,
                                                 const int* __restrict__ oi1, const float* __restrict__ owt,
                                                 float* __restrict__ out) {
    int p = blockIdx.x * 256 + threadIdx.x;
    if (p >= kNPF) return;
    int lat = p / kWF;
    int p_lon = p - lat * kWF;

    int i0r[3], i1r[3];
    float awr[3];
#pragma unroll
    for (int r = 0; r < 3; r++) {
        int Lr = lat - 1 + r;
        Lr = Lr < 0 ? 0 : (Lr > kHF - 1 ? kHF - 1 : Lr);
        i0r[r] = li0[Lr]; i1r[r] = li1[Lr]; awr[r] = lwt[Lr];
    }
    int F = min(i0r[0], min(i0r[1], i0r[2]));

    float wrow[3][3];
#pragma unroll
    for (int r = 0; r < 3; r++) {
        int r0 = i0r[r] - F, r1 = i1r[r] - F;
#pragma unroll
        for (int pr = 0; pr < 3; pr++) {
            float wv = 0.0f;
            if (pr == r0) wv += 1.0f - awr[r];
            if (pr == r1) wv += awr[r];
            wrow[r][pr] = wv;
        }
    }

    int o0d[3], o1d[3];
    float owd[3];
#pragma unroll
    for (int d = 0; d < 3; d++) {
        int lm = (p_lon + d - 1 + kWF) % kWF;
        o0d[d] = oi0[lm]; o1d[d] = oi1[lm]; owd[d] = owt[lm];
    }
    int G = o0d[0];
    float wcol[3][3];
#pragma unroll
    for (int d = 0; d < 3; d++) {
        int c0 = (o0d[d] - G + kWP) % kWP;
        int c1 = (o1d[d] - G + kWP) % kWP;
#pragma unroll
        for (int pc = 0; pc < 3; pc++) {
            float wv = 0.0f;
            if (pc == c0) wv += 1.0f - owd[d];
            if (pc == c1) wv += owd[d];
            wcol[d][pc] = wv;
        }
    }

    float vv[kK][kNB];
#pragma unroll
    for (int k = 0; k < kK; k++) {
        const float* vp = dvals + ((size_t)k * kNPF + p) * kNB;
#pragma unroll
        for (int n = 0; n < kNB; n += 2) {
            float2 v2 = *(const float2*)(vp + n);
            vv[k][n] = v2.x; vv[k][n + 1] = v2.y;
        }
    }

    const int RR[kNB] = {1, 1, 1, 2, 0, 2};
    const int CC[kNB] = {1, 2, 0, 1, 1, 2};
    float ck[kK][3][3];
#pragma unroll
    for (int k = 0; k < kK; k++)
#pragma unroll
        for (int pr = 0; pr < 3; pr++)
#pragma unroll
            for (int pc = 0; pc < 3; pc++) {
                float s = 0.0f;
#pragma unroll
                for (int n = 0; n < kNB; n++)
                    s = fmaf(vv[k][n], wrow[RR[n]][pr] * wcol[CC[n]][pc], s);
                ck[k][pr][pc] = s;
            }

    int ofs[3][3];
#pragma unroll
    for (int pr = 0; pr < 3; pr++) {
        int row = F + pr; row = row > kHP - 1 ? kHP - 1 : row;
#pragma unroll
        for (int pc = 0; pc < 3; pc++) {
            int col = (G + pc) % kWP;
            ofs[pr][pc] = row * kWP + col;
        }
    }

    float acc[kCOUT];
#pragma unroll
    for (int o = 0; o < kCOUT; o++) acc[o] = 0.0f;

    const float* wp = dwT;
    const float* hi = h;
#pragma unroll 2
    for (int i = 0; i < kCE; i++) {
        float hv[3][3];
#pragma unroll
        for (int pr = 0; pr < 3; pr++)
#pragma unroll
            for (int pc = 0; pc < 3; pc++)
                hv[pr][pc] = hi[ofs[pr][pc]];
        float z[kK];
#pragma unroll
        for (int k = 0; k < kK; k++) {
            float s = 0.0f;
#pragma unroll
            for (int pr = 0; pr < 3; pr++)
#pragma unroll
                for (int pc = 0; pc < 3; pc++)
                    s = fmaf(ck[k][pr][pc], hv[pr][pc], s);
            z[k] = s;
        }
#pragma unroll
        for (int o = 0; o < kCOUT; o++) {
            float s = acc[o];
#pragma unroll
            for (int k = 0; k < kK; k++) s = fmaf(wp[o * kK + k], z[k], s);
            acc[o] = s;
        }
        wp += kCOUT * kK;
        hi += kNP;
    }

#pragma unroll
    for (int o = 0; o < kCOUT; o++) out[(size_t)o * kNPF + p] = acc[o];
}

// ---------------- host launcher ----------------
extern "C" void kernel_launch(void* const* d_in, const int* in_sizes, int n_in,
                              void* d_out, int out_size, void* d_ws, size_t ws_size,
                              hipStream_t stream) {
    const float* x         = (const float*)d_in[0];
    const int*   enc_idx   = (const int*)d_in[1];
    const float* enc_vals  = (const float*)d_in[2];
    const float* enc_w     = (const float*)d_in[3];
    const int*   proc_idx  = (const int*)d_in[4];
    const float* proc_vals = (const float*)d_in[5];
    const float* lw        = (const float*)d_in[6];
    const float* gw        = (const float*)d_in[7];
    const float* Pw        = (const float*)d_in[8];
    const float* Pi        = (const float*)d_in[9];
    const float* m1        = (const float*)d_in[10];
    const float* m2        = (const float*)d_in[11];
    const float* ls        = (const float*)d_in[12];
    const int*   li0       = (const int*)d_in[13];
    const int*   li1       = (const int*)d_in[14];
    const float* lwt       = (const float*)d_in[15];
    const int*   oi0       = (const int*)d_in[16];
    const int*   oi1       = (const int*)d_in[17];
    const float* owt       = (const float*)d_in[18];
    const int*   dec_idx   = (const int*)d_in[19];
    const float* dec_vals  = (const float*)d_in[20];
    const float* dec_w     = (const float*)d_in[21];
    float* out = (float*)d_out;
    (void)dec_idx;

    float* ws = (float*)d_ws;
    size_t off = 0;
    auto alloc = [&](size_t n) { float* p = ws + off; off += n; return p; };
    float*  h    = alloc((size_t)kCE * kNP);
    float2* xc   = (float2*)alloc((size_t)2 * kCE * kHP * kM);
    float2* c2c  = (float2*)alloc((size_t)2 * kCE * kL * kM);
    float*  dx   = alloc((size_t)kCE * kNP);
    float2* fcs  = (float2*)alloc((size_t)2 * kM * kWP);
    float2* icn  = (float2*)alloc((size_t)2 * kM * kWP);
    float*  PwT  = alloc((size_t)kL * kM * kHP);
    float*  PiT  = alloc((size_t)kL * kM * kHP);
    float*  dwT  = alloc((size_t)kCOUT * kCE * kK);
    (void)ws_size; (void)in_sizes; (void)n_in; (void)out_size;

    dim3 B(256);
    auto nb = [](long long n) { return dim3((unsigned)((n + 255) / 256)); };

    k_prep1<<<nb(kM * kWP), B, 0, stream>>>(fcs, icn, dec_w, dwT);
    k_prep2<<<nb(2LL * kL * kM * kHP), B, 0, stream>>>(Pw, Pi, PwT, PiT);

    // encoder
    k_disco<kCIN, kCE, 8><<<nb((long long)kNP * 8), B, 0, stream>>>(
        x, kNPF, enc_idx, enc_vals, enc_w, h, kNP);

    int nMlpBlocks = (kNP + kTP - 1) / kTP;
    for (int i = 0; i < kNL; i++) {
        if (i % 2 == 0) {
            const float* gwl = gw + (size_t)(i / 2) * kCE * kCE * kL;
            k_rfft2<<<nb((long long)kCE * kHP * kM), B, 0, stream>>>(h, fcs, xc);
            k_sht_gmix<<<dim3(kL * 5), B, 0, stream>>>(PwT, xc, gwl, c2c);
            k_isht_irfft<<<dim3(kCE * kHP), dim3(192), 0, stream>>>(PiT, c2c, icn, dx);
        } else {
            const float* lwl = lw + (size_t)(i / 2) * kCE * kCE * kK;
            k_disco<kCE, kCE, 8><<<nb((long long)kNP * 8), B, 0, stream>>>(
                h, kNP, proc_idx, proc_vals, lwl, dx, kNP);
        }
        k_mlp_f<<<dim3(nMlpBlocks), B, 0, stream>>>(
            m1 + (size_t)i * kHD * kCE, m2 + (size_t)i * kCE * kHD, ls + (size_t)i * kCE, dx, h);
    }

    // decoder: per-point 3x3 stencil, direct from global (round-8 form)
    k_dconv_d<<<nb((long long)kNPF), B, 0, stream>>>(h, dec_vals, dwT,
                                                     li0, li1, lwt, oi0, oi1, owt, out);
}